// Round 16
// baseline (465.861 us; speedup 1.0000x reference)
//
#include <hip/hip_runtime.h>

// ---------------------------------------------------------------------------
// IAGNN: h=relu(x@W_in+b); 4x { gate=sig(a_s[src]+a_d[dst]+ba); m=h@Wm+bm;
//   agg=seg_sum(gate*m[src],dst); pre=agg+h@Wr+br; h=relu(featnorm(pre)) };
//   pooled=seg_sum(h,batch); logits=(relu(pooled@W1+b1)@W2+b2)/2
// R16: R15 (453us) + agg 64 nodes/block (halve stats-atomic epilogue),
//   stats replicas 8->16 (3rd application of the proven contention lever),
//   longer-pole-first block order in merged kernels (hist/bucket blocks get
//   low blockIds so their atomic/scatter tail overlaps GEMM, not after it).
//   LDS-pad conflict fix rejected: b128 needs 16B strides -> 2-way aliasing
//   is provably minimal and free (m136).
// ---------------------------------------------------------------------------

typedef __attribute__((ext_vector_type(8))) short short8;
typedef __attribute__((ext_vector_type(4))) float f32x4;
typedef __attribute__((ext_vector_type(4))) uint uintx4;

#define HDIM 128
#define NCOL_L 272      // 128 (Wm) + 128 (Wr) + 2 (Wa) + 14 pad -> 17 n-tiles
#define LDSTRIDE 136    // +8 bf16 pad
#define EPSN 1e-5f
#define NGRAPH 64
#define SMEM_B (144 * LDSTRIDE * 2)   // 39,168 B: B-tile staging footprint
#define SMEM_L (SMEM_B + 1024)        // + S/T buffer (256 floats)
#define NREP 16                       // stats replicas per layer

__device__ __forceinline__ ushort f2bf(float f) {
    uint u = __float_as_uint(f);
    u += 0x7FFFu + ((u >> 16) & 1u);   // RNE
    return (ushort)(u >> 16);
}
__device__ __forceinline__ float bflo(uint u) { return __uint_as_float(u << 16); }
__device__ __forceinline__ float bfhi(uint u) { return __uint_as_float(u & 0xffff0000u); }
__device__ __forceinline__ f32x4 mfma_bf16(short8 a, short8 b, f32x4 c) {
    return __builtin_amdgcn_mfma_f32_16x16x32_bf16(a, b, c, 0, 0, 0);
}

// ---- weight prep (bf16 B^T) + zero-init (counts/cursor/stats/flags) -------
// stats: 4 layers x NREP replicas x 256 floats = 16384 floats
__global__ void k_prep(const float* __restrict__ W_in, const float* __restrict__ Wa,
                       const float* __restrict__ Wm, const float* __restrict__ Wr,
                       ushort* __restrict__ Btin, ushort* __restrict__ Btl,
                       int* __restrict__ counts, int* __restrict__ cursor,
                       float* __restrict__ stats, int* __restrict__ flags, int Nn)
{
    int idx = blockIdx.x * 256 + threadIdx.x;
    if (idx < Nn) { counts[idx] = 0; cursor[idx] = 0; }
    if (idx < 16384) stats[idx] = 0.f;
    if (idx < 256) flags[idx] = 0;
    if (idx < 128 * 128) {
        int n = idx >> 7, k = idx & 127;
        Btin[n * 128 + k] = f2bf(W_in[k * 128 + n]);
    } else {
        int j = idx - 128 * 128;
        int l = j / (NCOL_L * 128);
        int rem = j % (NCOL_L * 128);
        int n = rem >> 7, k = rem & 127;
        float v = 0.f;
        if (n < 128)        v = Wm[l * 16384 + k * 128 + n];
        else if (n < 256)   v = Wr[l * 16384 + k * 128 + (n - 128)];
        else if (n == 256)  v = Wa[l * 256 + k];
        else if (n == 257)  v = Wa[l * 256 + 128 + k];
        Btl[j] = f2bf(v);
    }
}

// =================== GEMM device bodies (shared by kernels) ================

// h = relu(x @ W_in + b) for block 'bid' (128 rows); smem >= 128*LDSTRIDE*2 B
__device__ __forceinline__ void gemm_in_body(
    char* smem, int bid, const float* __restrict__ X, const ushort* __restrict__ Bt,
    const float* __restrict__ bias, ushort* __restrict__ Hout, int M)
{
    ushort* Bs = (ushort*)smem;
    int tid = threadIdx.x;
    for (int idx = tid; idx < 128 * 16; idx += 256) {
        int col = idx >> 4, kk = (idx & 15) << 3;
        uintx4 v = *(const uintx4*)(Bt + col * 128 + kk);
        *(uintx4*)(&Bs[col * LDSTRIDE + kk]) = v;
    }
    int wave = tid >> 6, lane = tid & 63, quad = lane >> 4, l16 = lane & 15;
    int rowbase = bid * 128 + wave * 32;
    short8 zf = {0,0,0,0,0,0,0,0};
    short8 afrag[2][4];
    for (int mt = 0; mt < 2; mt++) {
        int row = rowbase + mt * 16 + l16;
        if (row < M) {
            const float* ap = X + (size_t)row * 128;
            for (int kt = 0; kt < 4; kt++) {
                const float4* p = (const float4*)(ap + kt * 32 + quad * 8);
                float4 f0 = p[0], f1 = p[1];
                union { ushort us[8]; short8 v; } cv;
                cv.us[0]=f2bf(f0.x); cv.us[1]=f2bf(f0.y); cv.us[2]=f2bf(f0.z); cv.us[3]=f2bf(f0.w);
                cv.us[4]=f2bf(f1.x); cv.us[5]=f2bf(f1.y); cv.us[6]=f2bf(f1.z); cv.us[7]=f2bf(f1.w);
                afrag[mt][kt] = cv.v;
            }
        } else {
            for (int kt = 0; kt < 4; kt++) afrag[mt][kt] = zf;
        }
    }
    __syncthreads();
    for (int nt = 0; nt < 8; nt++) {
        f32x4 acc0 = {0.f,0.f,0.f,0.f}, acc1 = {0.f,0.f,0.f,0.f};
        for (int kt = 0; kt < 4; kt++) {
            short8 b = *(const short8*)(&Bs[(nt * 16 + l16) * LDSTRIDE + kt * 32 + quad * 8]);
            acc0 = mfma_bf16(afrag[0][kt], b, acc0);
            acc1 = mfma_bf16(afrag[1][kt], b, acc1);
        }
        int colg = nt * 16 + l16;
        float bv = bias[colg];
        for (int r = 0; r < 4; r++) {
            int row0 = rowbase + quad * 4 + r;
            if (row0 < M) {
                float v = acc0[r] + bv; v = v > 0.f ? v : 0.f;
                Hout[(size_t)row0 * 128 + colg] = f2bf(v);
            }
            int row1 = rowbase + 16 + quad * 4 + r;
            if (row1 < M) {
                float v = acc1[r] + bv; v = v > 0.f ? v : 0.f;
                Hout[(size_t)row1 * 128 + colg] = f2bf(v);
            }
        }
    }
}

// One column-phase of the layer GEMM for a 128-row block 'bid'.
// phase 0: cols [0,128)   (Wm) -> Mout (+bm)
// phase 1: cols [128,272) (Wr|Wa|pad) -> Rout (+br), asrc, adst
// FUSED: A = relu(norm(pre_prev)); S/T computed cooperatively into LDS once
// per block (nstats = NREP x 256 replica base). A loads issued before B
// staging to overlap HBM latency.
template<bool FUSED>
__device__ __forceinline__ void gemm_layer_phase(
    char* smem, int bid, int phase, const ushort* __restrict__ Asrc,
    const float* __restrict__ nstats, const float* __restrict__ ngamma,
    const float* __restrict__ nbeta,
    const ushort* __restrict__ Bt,
    const float* __restrict__ bm, const float* __restrict__ br,
    ushort* __restrict__ Mout, ushort* __restrict__ Rout,
    float* __restrict__ asrc, float* __restrict__ adst, int M)
{
    ushort* Bs = (ushort*)smem;
    float* STs = (float*)(smem + SMEM_B);   // S[0..127] | T[128..255]
    int tid = threadIdx.x;
    int wave = tid >> 6, lane = tid & 63, quad = lane >> 4, l16 = lane & 15;
    int rowbase = bid * 128 + wave * 32;
    short8 zf = {0,0,0,0,0,0,0,0};
    short8 afrag[2][4];
    uintx4 pv[2][4];
    bool rowok[2];
    // 1. issue A loads first (HBM latency overlaps B staging)
    for (int mt = 0; mt < 2; mt++) {
        int row = rowbase + mt * 16 + l16;
        rowok[mt] = row < M;
        if (FUSED) {
            if (rowok[mt]) {
                for (int kt = 0; kt < 4; kt++)
                    pv[mt][kt] = *(const uintx4*)(Asrc + (size_t)row * 128 + kt * 32 + quad * 8);
            }
        } else {
            for (int kt = 0; kt < 4; kt++) {
                afrag[mt][kt] = rowok[mt]
                    ? *(const short8*)(Asrc + (size_t)row * 128 + kt * 32 + quad * 8) : zf;
            }
        }
    }
    // 2. stage B tile
    const int ncols = phase ? 144 : 128;
    const int colbase = phase ? 128 : 0;
    for (int idx = tid; idx < ncols * 16; idx += 256) {
        int col = idx >> 4, kk = (idx & 15) << 3;
        uintx4 v = *(const uintx4*)(Bt + (size_t)(colbase + col) * 128 + kk);
        *(uintx4*)(&Bs[col * LDSTRIDE + kk]) = v;
    }
    // 3. cooperative S/T (once per block, threads 0..127)
    if (FUSED && tid < 128) {
        float sm = 0.f, sq = 0.f;
        #pragma unroll
        for (int rep = 0; rep < NREP; rep++) {
            sm += nstats[rep * 256 + tid];
            sq += nstats[rep * 256 + 128 + tid];
        }
        float invN = 1.f / (float)M;
        float mu = sm * invN;
        float rs = rsqrtf(sq * invN - mu * mu + EPSN);
        float Sx = rs * ngamma[tid];
        STs[tid] = Sx;
        STs[128 + tid] = nbeta[tid] - mu * Sx;
    }
    __syncthreads();
    // 4. convert A (FUSED): relu(pre*S+T) -> bf16 frags, S/T from LDS
    if (FUSED) {
        for (int kt = 0; kt < 4; kt++) {
            int kb = kt * 32 + quad * 8;
            float4 Sv0 = *(const float4*)&STs[kb];
            float4 Sv1 = *(const float4*)&STs[kb + 4];
            float4 Tv0 = *(const float4*)&STs[128 + kb];
            float4 Tv1 = *(const float4*)&STs[128 + kb + 4];
            float S[8] = {Sv0.x, Sv0.y, Sv0.z, Sv0.w, Sv1.x, Sv1.y, Sv1.z, Sv1.w};
            float T[8] = {Tv0.x, Tv0.y, Tv0.z, Tv0.w, Tv1.x, Tv1.y, Tv1.z, Tv1.w};
            for (int mt = 0; mt < 2; mt++) {
                if (rowok[mt]) {
                    uintx4 p4 = pv[mt][kt];
                    float p[8] = {bflo(p4.x), bfhi(p4.x), bflo(p4.y), bfhi(p4.y),
                                  bflo(p4.z), bfhi(p4.z), bflo(p4.w), bfhi(p4.w)};
                    union { ushort us[8]; short8 v; } cv;
                    #pragma unroll
                    for (int j = 0; j < 8; j++) {
                        float v = p[j] * S[j] + T[j];
                        v = v > 0.f ? v : 0.f;
                        cv.us[j] = f2bf(v);
                    }
                    afrag[mt][kt] = cv.v;
                } else {
                    afrag[mt][kt] = zf;
                }
            }
        }
    }
    // 5. MFMA + store
    const int ntiles = phase ? 9 : 8;
    for (int nt = 0; nt < ntiles; nt++) {
        f32x4 acc0 = {0.f,0.f,0.f,0.f}, acc1 = {0.f,0.f,0.f,0.f};
        for (int kt = 0; kt < 4; kt++) {
            short8 b = *(const short8*)(&Bs[(nt * 16 + l16) * LDSTRIDE + kt * 32 + quad * 8]);
            acc0 = mfma_bf16(afrag[0][kt], b, acc0);
            acc1 = mfma_bf16(afrag[1][kt], b, acc1);
        }
        int colg = colbase + nt * 16 + l16;
        for (int half = 0; half < 2; half++) {
            f32x4 acc = half ? acc1 : acc0;
            int rb = rowbase + half * 16 + quad * 4;
            for (int r = 0; r < 4; r++) {
                int row = rb + r;
                if (row >= M) continue;
                float v = acc[r];
                if (colg < 128) {
                    Mout[(size_t)row * 128 + colg] = f2bf(v + bm[colg]);
                } else if (colg < 256) {
                    Rout[(size_t)row * 128 + (colg - 128)] = f2bf(v + br[colg - 128]);
                } else if (colg == 256) {
                    asrc[row] = v;
                } else if (colg == 257) {
                    adst[row] = v;
                }
            }
        }
    }
}

// ====== merged dispatch: [hist | gemm_in] (hist first: longer pole) ========
__global__ __launch_bounds__(256) void k_histgemm(
    const float* __restrict__ X, const ushort* __restrict__ Btin,
    const float* __restrict__ bias, ushort* __restrict__ Hout, int M,
    const int* __restrict__ dst, int* __restrict__ counts, int E, int nbE)
{
    __shared__ char smem[128 * LDSTRIDE * 2];
    int g = blockIdx.x;
    if (g < nbE) {
        int e = g * 256 + threadIdx.x;
        if (e < E) atomicAdd(&counts[dst[e]], 1);
    } else {
        gemm_in_body(smem, g - nbE, X, Btin, bias, Hout, M);
    }
}

// ====== standalone lookback scan + gstart (196 blocks, co-resident) ========
__global__ __launch_bounds__(256) void k_scang(
    const int* __restrict__ counts, int* __restrict__ offs,
    int* __restrict__ flags, const int* __restrict__ batch,
    int* __restrict__ gstart, int n, int nbN)
{
    __shared__ int sb[256];
    int g = blockIdx.x;
    int tid = threadIdx.x;
    int i = g * 256 + tid;
    int v = (i < n) ? counts[i] : 0;
    sb[tid] = v; __syncthreads();
    for (int off = 1; off < 256; off <<= 1) {
        int t = (tid >= off) ? sb[tid - off] : 0;
        __syncthreads();
        sb[tid] += t;
        __syncthreads();
    }
    int excl = sb[tid] - v;          // exclusive within block
    int total = sb[255];
    if (tid == 0) {
        __threadfence();
        atomicExch(&flags[g], total + 1);   // publish (device scope)
    }
    int pref = 0;
    for (int j = tid; j < g; j += 256) {
        int f;
        do { f = atomicAdd(&flags[j], 0); } while (f == 0);
        pref += f - 1;
    }
    __syncthreads();
    sb[tid] = pref; __syncthreads();
    for (int off = 128; off > 0; off >>= 1) {
        if (tid < off) sb[tid] += sb[tid + off];
        __syncthreads();
    }
    int prefix = sb[0];
    if (i < n) {
        offs[i] = prefix + excl;
        int b = batch[i];
        int prev = (i == 0) ? -1 : batch[i - 1];
        for (int gg = prev + 1; gg <= b; gg++) gstart[gg] = i;
        if (i == n - 1) for (int gg = b + 1; gg <= NGRAPH; gg++) gstart[gg] = n;
    }
    if (g == nbN - 1 && tid == 255) offs[n] = prefix + total;
}

// ==== merged dispatch: [bucket | gemm_layer l0 (2-phase)] (bucket first) ===
__global__ __launch_bounds__(256) void k_bucketgemm0(
    const ushort* __restrict__ Hin, const ushort* __restrict__ Bt,
    const float* __restrict__ bm, const float* __restrict__ br,
    ushort* __restrict__ Mout, ushort* __restrict__ Rout,
    float* __restrict__ asrc, float* __restrict__ adst, int M,
    const int* __restrict__ src, const int* __restrict__ dst,
    const int* __restrict__ offs, int* __restrict__ cursor,
    int* __restrict__ csrc, int E, int nbE)
{
    __shared__ char smem[SMEM_L];
    int g = blockIdx.x;
    if (g < nbE) {
        int e = g * 256 + threadIdx.x;
        if (e < E) {
            int d = dst[e];
            int slot = atomicAdd(&cursor[d], 1);
            csrc[offs[d] + slot] = src[e];
        }
    } else {
        int gb = g - nbE;
        gemm_layer_phase<false>(smem, gb >> 1, gb & 1, Hin,
                                nullptr, nullptr, nullptr,
                                Bt, bm, br, Mout, Rout, asrc, adst, M);
    }
}

// standalone fused-layer GEMM (layers 1..3), 2 column-phase blocks per row-block
__global__ __launch_bounds__(256) void k_gemm_layer(
    const ushort* __restrict__ Asrc,
    const float* __restrict__ nstats, const float* __restrict__ ngamma,
    const float* __restrict__ nbeta,
    const ushort* __restrict__ Bt,
    const float* __restrict__ bm, const float* __restrict__ br,
    ushort* __restrict__ Mout, ushort* __restrict__ Rout,
    float* __restrict__ asrc, float* __restrict__ adst, int M)
{
    __shared__ char smem[SMEM_L];
    gemm_layer_phase<true>(smem, blockIdx.x >> 1, blockIdx.x & 1, Asrc,
                           nstats, ngamma, nbeta,
                           Bt, bm, br, Mout, Rout, asrc, adst, M);
}

// ------ aggregation (frozen gather structure): 64 nodes/block --------------
// stats: block accumulates into replica (blockIdx & 15).
__global__ __launch_bounds__(256) void k_agg(
    const int* __restrict__ offs, const int* __restrict__ csrc,
    const float* __restrict__ asrc, const float* __restrict__ adst,
    const float* __restrict__ ba, const ushort* __restrict__ Mb,
    const ushort* __restrict__ Rb, ushort* __restrict__ preOut,
    float* __restrict__ stats, int Nn)
{
    __shared__ float s_acc[256];   // [0..127] sum, [128..255] sumsq per feature
    int tid = threadIdx.x;
    s_acc[tid] = 0.f;
    __syncthreads();
    int wave = tid >> 6, lane = tid & 63;
    int fi = lane & 15;        // feature slice: elems fi*8 .. fi*8+7
    int grp = lane >> 4;       // edge subgroup 0..3
    int nbase = blockIdx.x * 64 + wave * 16;
    float bav = ba[0];
    int offv = 0; float adv = 0.f;
    if (lane < 17) {
        int idx = nbase + lane; if (idx > Nn) idx = Nn;
        offv = offs[idx];
    }
    if (lane < 16) {
        int idx = nbase + lane;
        if (idx < Nn) adv = adst[idx] + bav;
    }
    int fs0 = fi * 8 + grp * 2;    // this lane's 2 stats features (bijective)
    float ps0 = 0, ps1 = 0, pq0 = 0, pq1 = 0;
    for (int ni = 0; ni < 16; ni++) {
        int node = nbase + ni;
        if (node >= Nn) break;
        int j0 = __shfl(offv, ni, 64);
        int j1 = __shfl(offv, ni + 1, 64);
        float ad = __shfl(adv, ni, 64);
        uint rv = *(const uint*)(Rb + (size_t)node * 128 + fs0);   // r prefetch
        float acc[8];
        #pragma unroll
        for (int k = 0; k < 8; k++) acc[k] = 0.f;
        for (int base = j0; base < j1; base += 64) {
            int cnt = j1 - base; if (cnt > 64) cnt = 64;
            int sv = 0; float gv = 0.f;
            if (lane < cnt) {
                sv = csrc[base + lane];
                float e = asrc[sv] + ad;
                gv = 1.f / (1.f + __expf(-e));
            }
            for (int i = 0; i < cnt; i += 16) {
                int s0 = __shfl(sv, i + grp, 64);
                int s1 = __shfl(sv, i + 4 + grp, 64);
                int s2 = __shfl(sv, i + 8 + grp, 64);
                int s3 = __shfl(sv, i + 12 + grp, 64);
                float g0 = __shfl(gv, i + grp, 64);
                float g1 = __shfl(gv, i + 4 + grp, 64);
                float g2 = __shfl(gv, i + 8 + grp, 64);
                float g3 = __shfl(gv, i + 12 + grp, 64);
                uintx4 m0 = *(const uintx4*)(Mb + (size_t)s0 * 128 + fi * 8);
                uintx4 m1 = *(const uintx4*)(Mb + (size_t)s1 * 128 + fi * 8);
                uintx4 m2 = *(const uintx4*)(Mb + (size_t)s2 * 128 + fi * 8);
                uintx4 m3 = *(const uintx4*)(Mb + (size_t)s3 * 128 + fi * 8);
                acc[0] += g0*bflo(m0.x) + g1*bflo(m1.x) + g2*bflo(m2.x) + g3*bflo(m3.x);
                acc[1] += g0*bfhi(m0.x) + g1*bfhi(m1.x) + g2*bfhi(m2.x) + g3*bfhi(m3.x);
                acc[2] += g0*bflo(m0.y) + g1*bflo(m1.y) + g2*bflo(m2.y) + g3*bflo(m3.y);
                acc[3] += g0*bfhi(m0.y) + g1*bfhi(m1.y) + g2*bfhi(m2.y) + g3*bfhi(m3.y);
                acc[4] += g0*bflo(m0.z) + g1*bflo(m1.z) + g2*bflo(m2.z) + g3*bflo(m3.z);
                acc[5] += g0*bfhi(m0.z) + g1*bfhi(m1.z) + g2*bfhi(m2.z) + g3*bfhi(m3.z);
                acc[6] += g0*bflo(m0.w) + g1*bflo(m1.w) + g2*bflo(m2.w) + g3*bflo(m3.w);
                acc[7] += g0*bfhi(m0.w) + g1*bfhi(m1.w) + g2*bfhi(m2.w) + g3*bfhi(m3.w);
            }
        }
        #pragma unroll
        for (int k = 0; k < 8; k++) {
            acc[k] += __shfl_xor(acc[k], 16, 64);
            acc[k] += __shfl_xor(acc[k], 32, 64);
        }
        float p0 = acc[grp * 2]     + bflo(rv);
        float p1 = acc[grp * 2 + 1] + bfhi(rv);
        uint pw = (uint)f2bf(p0) | ((uint)f2bf(p1) << 16);
        *(uint*)(preOut + (size_t)node * 128 + fs0) = pw;
        ps0 += p0; ps1 += p1; pq0 += p0 * p0; pq1 += p1 * p1;
    }
    atomicAdd(&s_acc[fs0], ps0);
    atomicAdd(&s_acc[fs0 + 1], ps1);
    atomicAdd(&s_acc[128 + fs0], pq0);
    atomicAdd(&s_acc[128 + fs0 + 1], pq1);
    __syncthreads();
    float* st = stats + ((blockIdx.x & (NREP - 1)) << 8);
    atomicAdd(&st[tid], s_acc[tid]);
}

// -- pool+MLP fused: block per graph; final norm+relu inline (NREP replicas) -
__global__ __launch_bounds__(256) void k_poolmlp(
    const ushort* __restrict__ PreB, const int* __restrict__ gstart,
    const float* __restrict__ stats, const float* __restrict__ gamma,
    const float* __restrict__ beta,
    const float* __restrict__ W1, const float* __restrict__ b1,
    const float* __restrict__ W2, const float* __restrict__ b2,
    float* __restrict__ out, int Nn)
{
    __shared__ float sred[512];
    __shared__ float Hd[64];
    int g = blockIdx.x;
    int n0 = gstart[g], n1 = gstart[g + 1];
    int wave = threadIdx.x >> 6, lane = threadIdx.x & 63;
    int f0 = lane * 2, f1 = f0 + 1;
    float invN = 1.f / (float)Nn;
    float sm0 = 0.f, sm1 = 0.f, sq0 = 0.f, sq1 = 0.f;
    #pragma unroll
    for (int rep = 0; rep < NREP; rep++) {
        sm0 += stats[rep * 256 + f0];
        sm1 += stats[rep * 256 + f1];
        sq0 += stats[rep * 256 + 128 + f0];
        sq1 += stats[rep * 256 + 128 + f1];
    }
    float mu0 = sm0 * invN, mu1 = sm1 * invN;
    float rs0 = rsqrtf(sq0 * invN - mu0 * mu0 + EPSN);
    float rs1 = rsqrtf(sq1 * invN - mu1 * mu1 + EPSN);
    float S0 = rs0 * gamma[f0], T0 = beta[f0] - mu0 * S0;
    float S1 = rs1 * gamma[f1], T1 = beta[f1] - mu1 * S1;
    float a0 = 0.f, a1 = 0.f;
    int cntn = n1 - n0;
    int chunk = (cntn + 3) >> 2;
    int s = n0 + wave * chunk;
    int e = s + chunk; if (e > n1) e = n1;
    int n = s;
    for (; n + 8 <= e; n += 8) {
        uint u0 = *(const uint*)(PreB + (size_t)(n + 0) * 128 + f0);
        uint u1 = *(const uint*)(PreB + (size_t)(n + 1) * 128 + f0);
        uint u2 = *(const uint*)(PreB + (size_t)(n + 2) * 128 + f0);
        uint u3 = *(const uint*)(PreB + (size_t)(n + 3) * 128 + f0);
        uint u4 = *(const uint*)(PreB + (size_t)(n + 4) * 128 + f0);
        uint u5 = *(const uint*)(PreB + (size_t)(n + 5) * 128 + f0);
        uint u6 = *(const uint*)(PreB + (size_t)(n + 6) * 128 + f0);
        uint u7 = *(const uint*)(PreB + (size_t)(n + 7) * 128 + f0);
        uint us[8] = {u0,u1,u2,u3,u4,u5,u6,u7};
        #pragma unroll
        for (int k = 0; k < 8; k++) {
            float v0 = bflo(us[k]) * S0 + T0; v0 = v0 > 0.f ? v0 : 0.f;
            float v1 = bfhi(us[k]) * S1 + T1; v1 = v1 > 0.f ? v1 : 0.f;
            a0 += v0; a1 += v1;
        }
    }
    for (; n < e; n++) {
        uint u = *(const uint*)(PreB + (size_t)n * 128 + f0);
        float v0 = bflo(u) * S0 + T0; v0 = v0 > 0.f ? v0 : 0.f;
        float v1 = bfhi(u) * S1 + T1; v1 = v1 > 0.f ? v1 : 0.f;
        a0 += v0; a1 += v1;
    }
    sred[wave * 128 + f0] = a0;
    sred[wave * 128 + f1] = a1;
    __syncthreads();
    if (threadIdx.x < 128) {
        float sv = sred[threadIdx.x] + sred[128 + threadIdx.x]
                 + sred[256 + threadIdx.x] + sred[384 + threadIdx.x];
        sred[threadIdx.x] = sv;            // pooled row lives in sred[0..127]
    }
    __syncthreads();
    int j = threadIdx.x;
    if (j < 64) {
        float s0 = 0.f, s1 = 0.f, s2 = 0.f, s3 = 0.f;
        for (int k = 0; k < 128; k += 4) {
            s0 += sred[k]     * W1[k * 64 + j];
            s1 += sred[k + 1] * W1[(k + 1) * 64 + j];
            s2 += sred[k + 2] * W1[(k + 2) * 64 + j];
            s3 += sred[k + 3] * W1[(k + 3) * 64 + j];
        }
        float sv = b1[j] + ((s0 + s1) + (s2 + s3));
        Hd[j] = sv > 0.f ? sv : 0.f;
    }
    __syncthreads();
    if (j < 10) {
        float t0 = 0.f, t1 = 0.f;
        for (int k = 0; k < 64; k += 2) {
            t0 += Hd[k]     * W2[k * 10 + j];
            t1 += Hd[k + 1] * W2[(k + 1) * 10 + j];
        }
        out[g * 10 + j] = (b2[j] + t0 + t1) * 0.5f;   // / TEMP
    }
}

// ---------------------------------------------------------------------------
extern "C" void kernel_launch(void* const* d_in, const int* in_sizes, int n_in,
                              void* d_out, int out_size, void* d_ws, size_t ws_size,
                              hipStream_t stream)
{
    const float* x     = (const float*)d_in[0];
    const int*   ei    = (const int*)  d_in[1];
    const int*   batch = (const int*)  d_in[2];
    const float* W_in  = (const float*)d_in[3];
    const float* b_in  = (const float*)d_in[4];
    const float* Wa    = (const float*)d_in[5];
    const float* ba    = (const float*)d_in[6];
    const float* Wm    = (const float*)d_in[7];
    const float* bm    = (const float*)d_in[8];
    const float* Wr    = (const float*)d_in[9];
    const float* br    = (const float*)d_in[10];
    const float* gamma = (const float*)d_in[11];
    const float* beta  = (const float*)d_in[12];
    const float* W1    = (const float*)d_in[13];
    const float* b1    = (const float*)d_in[14];
    const float* W2    = (const float*)d_in[15];
    const float* b2    = (const float*)d_in[16];
    float* out = (float*)d_out;

    const int N = in_sizes[0] / 128;    // 50000
    const int E = in_sizes[1] / 2;      // 600000
    const int* e_src = ei;
    const int* e_dst = ei + E;

    // -------- workspace layout (bytes) --------
    char* ws = (char*)d_ws;
    ushort* h_b    = (ushort*)(ws + 0);               // 12,800,000  bf16 h (layer-0 A)
    ushort* m_b    = (ushort*)(ws + 12800000);        // 12,800,000  bf16 m
    ushort* r_b    = (ushort*)(ws + 25600000);        // 12,800,000  bf16 r
    ushort* pre_b  = (ushort*)(ws + 38400000);        // 12,800,000  bf16 pre
    float*  asrc   = (float*) (ws + 51200000);        //    200,000
    float*  adst   = (float*) (ws + 51400000);        //    200,000
    int*    counts = (int*)   (ws + 51600000);        //    200,000
    int*    cursor = (int*)   (ws + 51800000);        //    200,000
    int*    offs   = (int*)   (ws + 52000000);        //    200,064 (N+1)
    int*    csrc   = (int*)   (ws + 52200064);        //  2,400,000
    int*    flags  = (int*)   (ws + 54600064);        //      1,024 (scan lookback)
    ushort* Btin   = (ushort*)(ws + 54601088);        //     32,768
    ushort* Btl    = (ushort*)(ws + 54633856);        //    278,528
    float*  stats  = (float*) (ws + 54912384);        //     65,536 (4 x 16 x 256)
    int*    gstart = (int*)   (ws + 54977920);        //        260 (G+1)
    (void)ws_size; (void)n_in; (void)out_size;

    const int nbE = (E + 255) / 256;          // 2344
    const int nbN = (N + 255) / 256;          // 196
    const int nbG = (N + 127) / 128;          // 391 gemm row-blocks
    const int nbA = (N + 63) / 64;            // 782 agg blocks (64 nodes each)

    k_prep<<<608, 256, 0, stream>>>(W_in, Wa, Wm, Wr, Btin, Btl,
                                    counts, cursor, stats, flags, N);
    // [hist | gemm_in] -- hist first (longer atomic pole)
    k_histgemm<<<nbE + nbG, 256, 0, stream>>>(x, Btin, b_in, h_b, N,
                                              e_dst, counts, E, nbE);
    // lookback scan + gstart (needs counts)
    k_scang<<<nbN, 256, 0, stream>>>(counts, offs, flags, batch, gstart, N, nbN);
    // [bucket | gemm_layer l0 (2-phase)] -- bucket first (longer scatter pole)
    k_bucketgemm0<<<nbE + 2 * nbG, 256, 0, stream>>>(
        h_b, Btl, bm, br, m_b, r_b, asrc, adst, N,
        e_src, e_dst, offs, cursor, csrc, E, nbE);

    for (int l = 0; l < 4; l++) {
        if (l > 0) {
            k_gemm_layer<<<2 * nbG, 256, 0, stream>>>(
                pre_b, stats + (l - 1) * 4096, gamma + (l - 1) * 128, beta + (l - 1) * 128,
                Btl + l * (NCOL_L * 128), bm + l * 128, br + l * 128,
                m_b, r_b, asrc, adst, N);
        }
        k_agg<<<nbA, 256, 0, stream>>>(offs, csrc, asrc, adst, ba + l,
                                       m_b, r_b, pre_b, stats + l * 4096, N);
    }

    k_poolmlp<<<NGRAPH, 256, 0, stream>>>(pre_b, gstart, stats + 3 * 4096,
                                          gamma + 384, beta + 384,
                                          W1, b1, W2, b2, out, N);
}

// Round 17
// 448.673 us; speedup vs baseline: 1.0383x; 1.0383x over previous
//
#include <hip/hip_runtime.h>

// ---------------------------------------------------------------------------
// IAGNN: h=relu(x@W_in+b); 4x { gate=sig(a_s[src]+a_d[dst]+ba); m=h@Wm+bm;
//   agg=seg_sum(gate*m[src],dst); pre=agg+h@Wr+br; h=relu(featnorm(pre)) };
//   pooled=seg_sum(h,batch); logits=(relu(pooled@W1+b1)@W2+b2)/2
// R17: full revert to R15 (453us best). R16's three changes regressed (+13us):
//   scatter-first block order serialized the scatter wall against the GEMM
//   (lesson: compute-bound work first, latency-bound blocks fill in behind);
//   agg 64-node + NREP16 unproven. Config: GEMM-first merges, agg 32
//   nodes/block, NREP=8, cooperative S/T in LDS, 2-column-phase 128-row
//   layer GEMMs, lookback scan, pool+MLP fused.
// ---------------------------------------------------------------------------

typedef __attribute__((ext_vector_type(8))) short short8;
typedef __attribute__((ext_vector_type(4))) float f32x4;
typedef __attribute__((ext_vector_type(4))) uint uintx4;

#define HDIM 128
#define NCOL_L 272      // 128 (Wm) + 128 (Wr) + 2 (Wa) + 14 pad -> 17 n-tiles
#define LDSTRIDE 136    // +8 bf16 pad
#define EPSN 1e-5f
#define NGRAPH 64
#define SMEM_B (144 * LDSTRIDE * 2)   // 39,168 B: B-tile staging footprint
#define SMEM_L (SMEM_B + 1024)        // + S/T buffer (256 floats)
#define NREP 8                        // stats replicas per layer

__device__ __forceinline__ ushort f2bf(float f) {
    uint u = __float_as_uint(f);
    u += 0x7FFFu + ((u >> 16) & 1u);   // RNE
    return (ushort)(u >> 16);
}
__device__ __forceinline__ float bflo(uint u) { return __uint_as_float(u << 16); }
__device__ __forceinline__ float bfhi(uint u) { return __uint_as_float(u & 0xffff0000u); }
__device__ __forceinline__ f32x4 mfma_bf16(short8 a, short8 b, f32x4 c) {
    return __builtin_amdgcn_mfma_f32_16x16x32_bf16(a, b, c, 0, 0, 0);
}

// ---- weight prep (bf16 B^T) + zero-init (counts/cursor/stats/flags) -------
// stats: 4 layers x NREP replicas x 256 floats = 8192 floats
__global__ void k_prep(const float* __restrict__ W_in, const float* __restrict__ Wa,
                       const float* __restrict__ Wm, const float* __restrict__ Wr,
                       ushort* __restrict__ Btin, ushort* __restrict__ Btl,
                       int* __restrict__ counts, int* __restrict__ cursor,
                       float* __restrict__ stats, int* __restrict__ flags, int Nn)
{
    int idx = blockIdx.x * 256 + threadIdx.x;
    if (idx < Nn) { counts[idx] = 0; cursor[idx] = 0; }
    if (idx < 8192) stats[idx] = 0.f;
    if (idx < 256) flags[idx] = 0;
    if (idx < 128 * 128) {
        int n = idx >> 7, k = idx & 127;
        Btin[n * 128 + k] = f2bf(W_in[k * 128 + n]);
    } else {
        int j = idx - 128 * 128;
        int l = j / (NCOL_L * 128);
        int rem = j % (NCOL_L * 128);
        int n = rem >> 7, k = rem & 127;
        float v = 0.f;
        if (n < 128)        v = Wm[l * 16384 + k * 128 + n];
        else if (n < 256)   v = Wr[l * 16384 + k * 128 + (n - 128)];
        else if (n == 256)  v = Wa[l * 256 + k];
        else if (n == 257)  v = Wa[l * 256 + 128 + k];
        Btl[j] = f2bf(v);
    }
}

// =================== GEMM device bodies (shared by kernels) ================

// h = relu(x @ W_in + b) for block 'bid' (128 rows); smem >= 128*LDSTRIDE*2 B
__device__ __forceinline__ void gemm_in_body(
    char* smem, int bid, const float* __restrict__ X, const ushort* __restrict__ Bt,
    const float* __restrict__ bias, ushort* __restrict__ Hout, int M)
{
    ushort* Bs = (ushort*)smem;
    int tid = threadIdx.x;
    for (int idx = tid; idx < 128 * 16; idx += 256) {
        int col = idx >> 4, kk = (idx & 15) << 3;
        uintx4 v = *(const uintx4*)(Bt + col * 128 + kk);
        *(uintx4*)(&Bs[col * LDSTRIDE + kk]) = v;
    }
    int wave = tid >> 6, lane = tid & 63, quad = lane >> 4, l16 = lane & 15;
    int rowbase = bid * 128 + wave * 32;
    short8 zf = {0,0,0,0,0,0,0,0};
    short8 afrag[2][4];
    for (int mt = 0; mt < 2; mt++) {
        int row = rowbase + mt * 16 + l16;
        if (row < M) {
            const float* ap = X + (size_t)row * 128;
            for (int kt = 0; kt < 4; kt++) {
                const float4* p = (const float4*)(ap + kt * 32 + quad * 8);
                float4 f0 = p[0], f1 = p[1];
                union { ushort us[8]; short8 v; } cv;
                cv.us[0]=f2bf(f0.x); cv.us[1]=f2bf(f0.y); cv.us[2]=f2bf(f0.z); cv.us[3]=f2bf(f0.w);
                cv.us[4]=f2bf(f1.x); cv.us[5]=f2bf(f1.y); cv.us[6]=f2bf(f1.z); cv.us[7]=f2bf(f1.w);
                afrag[mt][kt] = cv.v;
            }
        } else {
            for (int kt = 0; kt < 4; kt++) afrag[mt][kt] = zf;
        }
    }
    __syncthreads();
    for (int nt = 0; nt < 8; nt++) {
        f32x4 acc0 = {0.f,0.f,0.f,0.f}, acc1 = {0.f,0.f,0.f,0.f};
        for (int kt = 0; kt < 4; kt++) {
            short8 b = *(const short8*)(&Bs[(nt * 16 + l16) * LDSTRIDE + kt * 32 + quad * 8]);
            acc0 = mfma_bf16(afrag[0][kt], b, acc0);
            acc1 = mfma_bf16(afrag[1][kt], b, acc1);
        }
        int colg = nt * 16 + l16;
        float bv = bias[colg];
        for (int r = 0; r < 4; r++) {
            int row0 = rowbase + quad * 4 + r;
            if (row0 < M) {
                float v = acc0[r] + bv; v = v > 0.f ? v : 0.f;
                Hout[(size_t)row0 * 128 + colg] = f2bf(v);
            }
            int row1 = rowbase + 16 + quad * 4 + r;
            if (row1 < M) {
                float v = acc1[r] + bv; v = v > 0.f ? v : 0.f;
                Hout[(size_t)row1 * 128 + colg] = f2bf(v);
            }
        }
    }
}

// One column-phase of the layer GEMM for a 128-row block 'bid'.
// phase 0: cols [0,128)   (Wm) -> Mout (+bm)
// phase 1: cols [128,272) (Wr|Wa|pad) -> Rout (+br), asrc, adst
// FUSED: A = relu(norm(pre_prev)); S/T computed cooperatively into LDS once
// per block (nstats = NREP x 256 replica base). A loads issued before B
// staging to overlap HBM latency.
template<bool FUSED>
__device__ __forceinline__ void gemm_layer_phase(
    char* smem, int bid, int phase, const ushort* __restrict__ Asrc,
    const float* __restrict__ nstats, const float* __restrict__ ngamma,
    const float* __restrict__ nbeta,
    const ushort* __restrict__ Bt,
    const float* __restrict__ bm, const float* __restrict__ br,
    ushort* __restrict__ Mout, ushort* __restrict__ Rout,
    float* __restrict__ asrc, float* __restrict__ adst, int M)
{
    ushort* Bs = (ushort*)smem;
    float* STs = (float*)(smem + SMEM_B);   // S[0..127] | T[128..255]
    int tid = threadIdx.x;
    int wave = tid >> 6, lane = tid & 63, quad = lane >> 4, l16 = lane & 15;
    int rowbase = bid * 128 + wave * 32;
    short8 zf = {0,0,0,0,0,0,0,0};
    short8 afrag[2][4];
    uintx4 pv[2][4];
    bool rowok[2];
    // 1. issue A loads first (HBM latency overlaps B staging)
    for (int mt = 0; mt < 2; mt++) {
        int row = rowbase + mt * 16 + l16;
        rowok[mt] = row < M;
        if (FUSED) {
            if (rowok[mt]) {
                for (int kt = 0; kt < 4; kt++)
                    pv[mt][kt] = *(const uintx4*)(Asrc + (size_t)row * 128 + kt * 32 + quad * 8);
            }
        } else {
            for (int kt = 0; kt < 4; kt++) {
                afrag[mt][kt] = rowok[mt]
                    ? *(const short8*)(Asrc + (size_t)row * 128 + kt * 32 + quad * 8) : zf;
            }
        }
    }
    // 2. stage B tile
    const int ncols = phase ? 144 : 128;
    const int colbase = phase ? 128 : 0;
    for (int idx = tid; idx < ncols * 16; idx += 256) {
        int col = idx >> 4, kk = (idx & 15) << 3;
        uintx4 v = *(const uintx4*)(Bt + (size_t)(colbase + col) * 128 + kk);
        *(uintx4*)(&Bs[col * LDSTRIDE + kk]) = v;
    }
    // 3. cooperative S/T (once per block, threads 0..127)
    if (FUSED && tid < 128) {
        float sm = 0.f, sq = 0.f;
        #pragma unroll
        for (int rep = 0; rep < NREP; rep++) {
            sm += nstats[rep * 256 + tid];
            sq += nstats[rep * 256 + 128 + tid];
        }
        float invN = 1.f / (float)M;
        float mu = sm * invN;
        float rs = rsqrtf(sq * invN - mu * mu + EPSN);
        float Sx = rs * ngamma[tid];
        STs[tid] = Sx;
        STs[128 + tid] = nbeta[tid] - mu * Sx;
    }
    __syncthreads();
    // 4. convert A (FUSED): relu(pre*S+T) -> bf16 frags, S/T from LDS
    if (FUSED) {
        for (int kt = 0; kt < 4; kt++) {
            int kb = kt * 32 + quad * 8;
            float4 Sv0 = *(const float4*)&STs[kb];
            float4 Sv1 = *(const float4*)&STs[kb + 4];
            float4 Tv0 = *(const float4*)&STs[128 + kb];
            float4 Tv1 = *(const float4*)&STs[128 + kb + 4];
            float S[8] = {Sv0.x, Sv0.y, Sv0.z, Sv0.w, Sv1.x, Sv1.y, Sv1.z, Sv1.w};
            float T[8] = {Tv0.x, Tv0.y, Tv0.z, Tv0.w, Tv1.x, Tv1.y, Tv1.z, Tv1.w};
            for (int mt = 0; mt < 2; mt++) {
                if (rowok[mt]) {
                    uintx4 p4 = pv[mt][kt];
                    float p[8] = {bflo(p4.x), bfhi(p4.x), bflo(p4.y), bfhi(p4.y),
                                  bflo(p4.z), bfhi(p4.z), bflo(p4.w), bfhi(p4.w)};
                    union { ushort us[8]; short8 v; } cv;
                    #pragma unroll
                    for (int j = 0; j < 8; j++) {
                        float v = p[j] * S[j] + T[j];
                        v = v > 0.f ? v : 0.f;
                        cv.us[j] = f2bf(v);
                    }
                    afrag[mt][kt] = cv.v;
                } else {
                    afrag[mt][kt] = zf;
                }
            }
        }
    }
    // 5. MFMA + store
    const int ntiles = phase ? 9 : 8;
    for (int nt = 0; nt < ntiles; nt++) {
        f32x4 acc0 = {0.f,0.f,0.f,0.f}, acc1 = {0.f,0.f,0.f,0.f};
        for (int kt = 0; kt < 4; kt++) {
            short8 b = *(const short8*)(&Bs[(nt * 16 + l16) * LDSTRIDE + kt * 32 + quad * 8]);
            acc0 = mfma_bf16(afrag[0][kt], b, acc0);
            acc1 = mfma_bf16(afrag[1][kt], b, acc1);
        }
        int colg = colbase + nt * 16 + l16;
        for (int half = 0; half < 2; half++) {
            f32x4 acc = half ? acc1 : acc0;
            int rb = rowbase + half * 16 + quad * 4;
            for (int r = 0; r < 4; r++) {
                int row = rb + r;
                if (row >= M) continue;
                float v = acc[r];
                if (colg < 128) {
                    Mout[(size_t)row * 128 + colg] = f2bf(v + bm[colg]);
                } else if (colg < 256) {
                    Rout[(size_t)row * 128 + (colg - 128)] = f2bf(v + br[colg - 128]);
                } else if (colg == 256) {
                    asrc[row] = v;
                } else if (colg == 257) {
                    adst[row] = v;
                }
            }
        }
    }
}

// ============ merged dispatch: [gemm_in | hist] (GEMM first) ===============
__global__ __launch_bounds__(256) void k_histgemm(
    const float* __restrict__ X, const ushort* __restrict__ Btin,
    const float* __restrict__ bias, ushort* __restrict__ Hout, int M,
    const int* __restrict__ dst, int* __restrict__ counts, int E, int nbG)
{
    __shared__ char smem[128 * LDSTRIDE * 2];
    int g = blockIdx.x;
    if (g < nbG) {
        gemm_in_body(smem, g, X, Btin, bias, Hout, M);
    } else {
        int e = (g - nbG) * 256 + threadIdx.x;
        if (e < E) atomicAdd(&counts[dst[e]], 1);
    }
}

// ====== standalone lookback scan + gstart (196 blocks, co-resident) ========
__global__ __launch_bounds__(256) void k_scang(
    const int* __restrict__ counts, int* __restrict__ offs,
    int* __restrict__ flags, const int* __restrict__ batch,
    int* __restrict__ gstart, int n, int nbN)
{
    __shared__ int sb[256];
    int g = blockIdx.x;
    int tid = threadIdx.x;
    int i = g * 256 + tid;
    int v = (i < n) ? counts[i] : 0;
    sb[tid] = v; __syncthreads();
    for (int off = 1; off < 256; off <<= 1) {
        int t = (tid >= off) ? sb[tid - off] : 0;
        __syncthreads();
        sb[tid] += t;
        __syncthreads();
    }
    int excl = sb[tid] - v;          // exclusive within block
    int total = sb[255];
    if (tid == 0) {
        __threadfence();
        atomicExch(&flags[g], total + 1);   // publish (device scope)
    }
    int pref = 0;
    for (int j = tid; j < g; j += 256) {
        int f;
        do { f = atomicAdd(&flags[j], 0); } while (f == 0);
        pref += f - 1;
    }
    __syncthreads();
    sb[tid] = pref; __syncthreads();
    for (int off = 128; off > 0; off >>= 1) {
        if (tid < off) sb[tid] += sb[tid + off];
        __syncthreads();
    }
    int prefix = sb[0];
    if (i < n) {
        offs[i] = prefix + excl;
        int b = batch[i];
        int prev = (i == 0) ? -1 : batch[i - 1];
        for (int gg = prev + 1; gg <= b; gg++) gstart[gg] = i;
        if (i == n - 1) for (int gg = b + 1; gg <= NGRAPH; gg++) gstart[gg] = n;
    }
    if (g == nbN - 1 && tid == 255) offs[n] = prefix + total;
}

// ===== merged dispatch: [gemm_layer l0 (2-phase) | bucket] (GEMM first) ====
__global__ __launch_bounds__(256) void k_bucketgemm0(
    const ushort* __restrict__ Hin, const ushort* __restrict__ Bt,
    const float* __restrict__ bm, const float* __restrict__ br,
    ushort* __restrict__ Mout, ushort* __restrict__ Rout,
    float* __restrict__ asrc, float* __restrict__ adst, int M,
    const int* __restrict__ src, const int* __restrict__ dst,
    const int* __restrict__ offs, int* __restrict__ cursor,
    int* __restrict__ csrc, int E, int nbG)
{
    __shared__ char smem[SMEM_L];
    int g = blockIdx.x;
    if (g < 2 * nbG) {
        gemm_layer_phase<false>(smem, g >> 1, g & 1, Hin,
                                nullptr, nullptr, nullptr,
                                Bt, bm, br, Mout, Rout, asrc, adst, M);
    } else {
        int e = (g - 2 * nbG) * 256 + threadIdx.x;
        if (e < E) {
            int d = dst[e];
            int slot = atomicAdd(&cursor[d], 1);
            csrc[offs[d] + slot] = src[e];
        }
    }
}

// standalone fused-layer GEMM (layers 1..3), 2 column-phase blocks per row-block
__global__ __launch_bounds__(256) void k_gemm_layer(
    const ushort* __restrict__ Asrc,
    const float* __restrict__ nstats, const float* __restrict__ ngamma,
    const float* __restrict__ nbeta,
    const ushort* __restrict__ Bt,
    const float* __restrict__ bm, const float* __restrict__ br,
    ushort* __restrict__ Mout, ushort* __restrict__ Rout,
    float* __restrict__ asrc, float* __restrict__ adst, int M)
{
    __shared__ char smem[SMEM_L];
    gemm_layer_phase<true>(smem, blockIdx.x >> 1, blockIdx.x & 1, Asrc,
                           nstats, ngamma, nbeta,
                           Bt, bm, br, Mout, Rout, asrc, adst, M);
}

// ------ aggregation (frozen gather structure): 32 nodes/block --------------
// stats: block accumulates into replica (blockIdx & 7).
__global__ __launch_bounds__(256) void k_agg(
    const int* __restrict__ offs, const int* __restrict__ csrc,
    const float* __restrict__ asrc, const float* __restrict__ adst,
    const float* __restrict__ ba, const ushort* __restrict__ Mb,
    const ushort* __restrict__ Rb, ushort* __restrict__ preOut,
    float* __restrict__ stats, int Nn)
{
    __shared__ float s_acc[256];   // [0..127] sum, [128..255] sumsq per feature
    int tid = threadIdx.x;
    s_acc[tid] = 0.f;
    __syncthreads();
    int wave = tid >> 6, lane = tid & 63;
    int fi = lane & 15;        // feature slice: elems fi*8 .. fi*8+7
    int grp = lane >> 4;       // edge subgroup 0..3
    int nbase = blockIdx.x * 32 + wave * 8;
    float bav = ba[0];
    int offv = 0; float adv = 0.f;
    if (lane < 9) {
        int idx = nbase + lane; if (idx > Nn) idx = Nn;
        offv = offs[idx];
    }
    if (lane < 8) {
        int idx = nbase + lane;
        if (idx < Nn) adv = adst[idx] + bav;
    }
    int fs0 = fi * 8 + grp * 2;    // this lane's 2 stats features (bijective)
    float ps0 = 0, ps1 = 0, pq0 = 0, pq1 = 0;
    for (int ni = 0; ni < 8; ni++) {
        int node = nbase + ni;
        if (node >= Nn) break;
        int j0 = __shfl(offv, ni, 64);
        int j1 = __shfl(offv, ni + 1, 64);
        float ad = __shfl(adv, ni, 64);
        uint rv = *(const uint*)(Rb + (size_t)node * 128 + fs0);   // r prefetch
        float acc[8];
        #pragma unroll
        for (int k = 0; k < 8; k++) acc[k] = 0.f;
        for (int base = j0; base < j1; base += 64) {
            int cnt = j1 - base; if (cnt > 64) cnt = 64;
            int sv = 0; float gv = 0.f;
            if (lane < cnt) {
                sv = csrc[base + lane];
                float e = asrc[sv] + ad;
                gv = 1.f / (1.f + __expf(-e));
            }
            for (int i = 0; i < cnt; i += 16) {
                int s0 = __shfl(sv, i + grp, 64);
                int s1 = __shfl(sv, i + 4 + grp, 64);
                int s2 = __shfl(sv, i + 8 + grp, 64);
                int s3 = __shfl(sv, i + 12 + grp, 64);
                float g0 = __shfl(gv, i + grp, 64);
                float g1 = __shfl(gv, i + 4 + grp, 64);
                float g2 = __shfl(gv, i + 8 + grp, 64);
                float g3 = __shfl(gv, i + 12 + grp, 64);
                uintx4 m0 = *(const uintx4*)(Mb + (size_t)s0 * 128 + fi * 8);
                uintx4 m1 = *(const uintx4*)(Mb + (size_t)s1 * 128 + fi * 8);
                uintx4 m2 = *(const uintx4*)(Mb + (size_t)s2 * 128 + fi * 8);
                uintx4 m3 = *(const uintx4*)(Mb + (size_t)s3 * 128 + fi * 8);
                acc[0] += g0*bflo(m0.x) + g1*bflo(m1.x) + g2*bflo(m2.x) + g3*bflo(m3.x);
                acc[1] += g0*bfhi(m0.x) + g1*bfhi(m1.x) + g2*bfhi(m2.x) + g3*bfhi(m3.x);
                acc[2] += g0*bflo(m0.y) + g1*bflo(m1.y) + g2*bflo(m2.y) + g3*bflo(m3.y);
                acc[3] += g0*bfhi(m0.y) + g1*bfhi(m1.y) + g2*bfhi(m2.y) + g3*bfhi(m3.y);
                acc[4] += g0*bflo(m0.z) + g1*bflo(m1.z) + g2*bflo(m2.z) + g3*bflo(m3.z);
                acc[5] += g0*bfhi(m0.z) + g1*bfhi(m1.z) + g2*bfhi(m2.z) + g3*bfhi(m3.z);
                acc[6] += g0*bflo(m0.w) + g1*bflo(m1.w) + g2*bflo(m2.w) + g3*bflo(m3.w);
                acc[7] += g0*bfhi(m0.w) + g1*bfhi(m1.w) + g2*bfhi(m2.w) + g3*bfhi(m3.w);
            }
        }
        #pragma unroll
        for (int k = 0; k < 8; k++) {
            acc[k] += __shfl_xor(acc[k], 16, 64);
            acc[k] += __shfl_xor(acc[k], 32, 64);
        }
        float p0 = acc[grp * 2]     + bflo(rv);
        float p1 = acc[grp * 2 + 1] + bfhi(rv);
        uint pw = (uint)f2bf(p0) | ((uint)f2bf(p1) << 16);
        *(uint*)(preOut + (size_t)node * 128 + fs0) = pw;
        ps0 += p0; ps1 += p1; pq0 += p0 * p0; pq1 += p1 * p1;
    }
    atomicAdd(&s_acc[fs0], ps0);
    atomicAdd(&s_acc[fs0 + 1], ps1);
    atomicAdd(&s_acc[128 + fs0], pq0);
    atomicAdd(&s_acc[128 + fs0 + 1], pq1);
    __syncthreads();
    float* st = stats + ((blockIdx.x & (NREP - 1)) << 8);
    atomicAdd(&st[tid], s_acc[tid]);
}

// -- pool+MLP fused: block per graph; final norm+relu inline (NREP replicas) -
__global__ __launch_bounds__(256) void k_poolmlp(
    const ushort* __restrict__ PreB, const int* __restrict__ gstart,
    const float* __restrict__ stats, const float* __restrict__ gamma,
    const float* __restrict__ beta,
    const float* __restrict__ W1, const float* __restrict__ b1,
    const float* __restrict__ W2, const float* __restrict__ b2,
    float* __restrict__ out, int Nn)
{
    __shared__ float sred[512];
    __shared__ float Hd[64];
    int g = blockIdx.x;
    int n0 = gstart[g], n1 = gstart[g + 1];
    int wave = threadIdx.x >> 6, lane = threadIdx.x & 63;
    int f0 = lane * 2, f1 = f0 + 1;
    float invN = 1.f / (float)Nn;
    float sm0 = 0.f, sm1 = 0.f, sq0 = 0.f, sq1 = 0.f;
    #pragma unroll
    for (int rep = 0; rep < NREP; rep++) {
        sm0 += stats[rep * 256 + f0];
        sm1 += stats[rep * 256 + f1];
        sq0 += stats[rep * 256 + 128 + f0];
        sq1 += stats[rep * 256 + 128 + f1];
    }
    float mu0 = sm0 * invN, mu1 = sm1 * invN;
    float rs0 = rsqrtf(sq0 * invN - mu0 * mu0 + EPSN);
    float rs1 = rsqrtf(sq1 * invN - mu1 * mu1 + EPSN);
    float S0 = rs0 * gamma[f0], T0 = beta[f0] - mu0 * S0;
    float S1 = rs1 * gamma[f1], T1 = beta[f1] - mu1 * S1;
    float a0 = 0.f, a1 = 0.f;
    int cntn = n1 - n0;
    int chunk = (cntn + 3) >> 2;
    int s = n0 + wave * chunk;
    int e = s + chunk; if (e > n1) e = n1;
    int n = s;
    for (; n + 8 <= e; n += 8) {
        uint u0 = *(const uint*)(PreB + (size_t)(n + 0) * 128 + f0);
        uint u1 = *(const uint*)(PreB + (size_t)(n + 1) * 128 + f0);
        uint u2 = *(const uint*)(PreB + (size_t)(n + 2) * 128 + f0);
        uint u3 = *(const uint*)(PreB + (size_t)(n + 3) * 128 + f0);
        uint u4 = *(const uint*)(PreB + (size_t)(n + 4) * 128 + f0);
        uint u5 = *(const uint*)(PreB + (size_t)(n + 5) * 128 + f0);
        uint u6 = *(const uint*)(PreB + (size_t)(n + 6) * 128 + f0);
        uint u7 = *(const uint*)(PreB + (size_t)(n + 7) * 128 + f0);
        uint us[8] = {u0,u1,u2,u3,u4,u5,u6,u7};
        #pragma unroll
        for (int k = 0; k < 8; k++) {
            float v0 = bflo(us[k]) * S0 + T0; v0 = v0 > 0.f ? v0 : 0.f;
            float v1 = bfhi(us[k]) * S1 + T1; v1 = v1 > 0.f ? v1 : 0.f;
            a0 += v0; a1 += v1;
        }
    }
    for (; n < e; n++) {
        uint u = *(const uint*)(PreB + (size_t)n * 128 + f0);
        float v0 = bflo(u) * S0 + T0; v0 = v0 > 0.f ? v0 : 0.f;
        float v1 = bfhi(u) * S1 + T1; v1 = v1 > 0.f ? v1 : 0.f;
        a0 += v0; a1 += v1;
    }
    sred[wave * 128 + f0] = a0;
    sred[wave * 128 + f1] = a1;
    __syncthreads();
    if (threadIdx.x < 128) {
        float sv = sred[threadIdx.x] + sred[128 + threadIdx.x]
                 + sred[256 + threadIdx.x] + sred[384 + threadIdx.x];
        sred[threadIdx.x] = sv;            // pooled row lives in sred[0..127]
    }
    __syncthreads();
    int j = threadIdx.x;
    if (j < 64) {
        float s0 = 0.f, s1 = 0.f, s2 = 0.f, s3 = 0.f;
        for (int k = 0; k < 128; k += 4) {
            s0 += sred[k]     * W1[k * 64 + j];
            s1 += sred[k + 1] * W1[(k + 1) * 64 + j];
            s2 += sred[k + 2] * W1[(k + 2) * 64 + j];
            s3 += sred[k + 3] * W1[(k + 3) * 64 + j];
        }
        float sv = b1[j] + ((s0 + s1) + (s2 + s3));
        Hd[j] = sv > 0.f ? sv : 0.f;
    }
    __syncthreads();
    if (j < 10) {
        float t0 = 0.f, t1 = 0.f;
        for (int k = 0; k < 64; k += 2) {
            t0 += Hd[k]     * W2[k * 10 + j];
            t1 += Hd[k + 1] * W2[(k + 1) * 10 + j];
        }
        out[g * 10 + j] = (b2[j] + t0 + t1) * 0.5f;   // / TEMP
    }
}

// ---------------------------------------------------------------------------
extern "C" void kernel_launch(void* const* d_in, const int* in_sizes, int n_in,
                              void* d_out, int out_size, void* d_ws, size_t ws_size,
                              hipStream_t stream)
{
    const float* x     = (const float*)d_in[0];
    const int*   ei    = (const int*)  d_in[1];
    const int*   batch = (const int*)  d_in[2];
    const float* W_in  = (const float*)d_in[3];
    const float* b_in  = (const float*)d_in[4];
    const float* Wa    = (const float*)d_in[5];
    const float* ba    = (const float*)d_in[6];
    const float* Wm    = (const float*)d_in[7];
    const float* bm    = (const float*)d_in[8];
    const float* Wr    = (const float*)d_in[9];
    const float* br    = (const float*)d_in[10];
    const float* gamma = (const float*)d_in[11];
    const float* beta  = (const float*)d_in[12];
    const float* W1    = (const float*)d_in[13];
    const float* b1    = (const float*)d_in[14];
    const float* W2    = (const float*)d_in[15];
    const float* b2    = (const float*)d_in[16];
    float* out = (float*)d_out;

    const int N = in_sizes[0] / 128;    // 50000
    const int E = in_sizes[1] / 2;      // 600000
    const int* e_src = ei;
    const int* e_dst = ei + E;

    // -------- workspace layout (bytes) --------
    char* ws = (char*)d_ws;
    ushort* h_b    = (ushort*)(ws + 0);               // 12,800,000  bf16 h (layer-0 A)
    ushort* m_b    = (ushort*)(ws + 12800000);        // 12,800,000  bf16 m
    ushort* r_b    = (ushort*)(ws + 25600000);        // 12,800,000  bf16 r
    ushort* pre_b  = (ushort*)(ws + 38400000);        // 12,800,000  bf16 pre
    float*  asrc   = (float*) (ws + 51200000);        //    200,000
    float*  adst   = (float*) (ws + 51400000);        //    200,000
    int*    counts = (int*)   (ws + 51600000);        //    200,000
    int*    cursor = (int*)   (ws + 51800000);        //    200,000
    int*    offs   = (int*)   (ws + 52000000);        //    200,064 (N+1)
    int*    csrc   = (int*)   (ws + 52200064);        //  2,400,000
    int*    flags  = (int*)   (ws + 54600064);        //      1,024 (scan lookback)
    ushort* Btin   = (ushort*)(ws + 54601088);        //     32,768
    ushort* Btl    = (ushort*)(ws + 54633856);        //    278,528
    float*  stats  = (float*) (ws + 54912384);        //     32,768 (4 layers x 8 reps x 256)
    int*    gstart = (int*)   (ws + 54945152);        //        260 (G+1)
    (void)ws_size; (void)n_in; (void)out_size;

    const int nbE = (E + 255) / 256;          // 2344
    const int nbN = (N + 255) / 256;          // 196
    const int nbG = (N + 127) / 128;          // 391 gemm row-blocks
    const int nbA = (N + 31) / 32;            // 1563 agg blocks

    k_prep<<<608, 256, 0, stream>>>(W_in, Wa, Wm, Wr, Btin, Btl,
                                    counts, cursor, stats, flags, N);
    // [gemm_in | hist] -- both depend only on prep/x
    k_histgemm<<<nbG + nbE, 256, 0, stream>>>(x, Btin, b_in, h_b, N,
                                              e_dst, counts, E, nbG);
    // lookback scan + gstart (needs counts)
    k_scang<<<nbN, 256, 0, stream>>>(counts, offs, flags, batch, gstart, N, nbN);
    // [gemm_layer l0 (2-phase) | bucket] -- gemm0 needs h; bucket needs offs
    k_bucketgemm0<<<2 * nbG + nbE, 256, 0, stream>>>(
        h_b, Btl, bm, br, m_b, r_b, asrc, adst, N,
        e_src, e_dst, offs, cursor, csrc, E, nbG);

    for (int l = 0; l < 4; l++) {
        if (l > 0) {
            k_gemm_layer<<<2 * nbG, 256, 0, stream>>>(
                pre_b, stats + (l - 1) * 2048, gamma + (l - 1) * 128, beta + (l - 1) * 128,
                Btl + l * (NCOL_L * 128), bm + l * 128, br + l * 128,
                m_b, r_b, asrc, adst, N);
        }
        k_agg<<<nbA, 256, 0, stream>>>(offs, csrc, asrc, adst, ba + l,
                                       m_b, r_b, pre_b, stats + l * 2048, N);
    }

    k_poolmlp<<<NGRAPH, 256, 0, stream>>>(pre_b, gstart, stats + 3 * 2048,
                                          gamma + 384, beta + 384,
                                          W1, b1, W2, b2, out, N);
}